// Round 9
// baseline (424.559 us; speedup 1.0000x reference)
//
#include <hip/hip_runtime.h>

#define NN 4096
#define NNP 4128   // padded row stride (shorts) to break 8KB channel aliasing
#define BROW 132   // bits row stride in u32 (528B, breaks 512B aliasing)
#define HEADS 4
#define H1PER 30
#define H1DIM 120
#define H2DIM 50

typedef short short8_t __attribute__((ext_vector_type(8)));
typedef float f32x4 __attribute__((ext_vector_type(4)));

__device__ __forceinline__ float lrelu(float x) { return x > 0.f ? x : 0.1f * x; }

__device__ __forceinline__ unsigned short bfrne(float x) {
  unsigned u = __float_as_uint(x);
  u += 0x7fffu + ((u >> 16) & 1u);
  return (unsigned short)(u >> 16);
}
__device__ __forceinline__ unsigned bfpk_rne(float lo, float hi) {
  return (unsigned)bfrne(lo) | ((unsigned)bfrne(hi) << 16);
}
__device__ __forceinline__ unsigned bfpk(float lo, float hi) {
  unsigned a = (__float_as_uint(lo) + 0x8000u) >> 16;
  unsigned b = (__float_as_uint(hi) + 0x8000u) & 0xffff0000u;
  return a | b;
}
// monotone float<->uint encoding for atomicMax-based float max
__device__ __forceinline__ unsigned fenc(float x) {
  unsigned u = __float_as_uint(x);
  return (u & 0x80000000u) ? ~u : (u | 0x80000000u);
}
__device__ __forceinline__ float fdec(unsigned u) {
  return (u & 0x80000000u) ? __uint_as_float(u ^ 0x80000000u) : __uint_as_float(~u);
}

#define GL16(g, l)                                                                        \
  __builtin_amdgcn_global_load_lds((const __attribute__((address_space(1))) unsigned int*)(g), \
                                   (__attribute__((address_space(3))) unsigned int*)(l), 16, 0, 0)

// ---------------- bitmask: adj(int32) -> 1 bit, padded rows ----------------
__global__ __launch_bounds__(256) void k_bits(const int* __restrict__ adj,
                                              unsigned long long* __restrict__ bits) {
  int n = blockIdx.x >> 2, r = blockIdx.x & 3;
  size_t base = (size_t)n * 4096 + r * 1024;
  int t = threadIdx.x;
  int v0 = adj[base + t];
  int v1 = adj[base + 256 + t];
  int v2 = adj[base + 512 + t];
  int v3 = adj[base + 768 + t];
  unsigned long long m0 = __ballot(v0 > 0);
  unsigned long long m1 = __ballot(v1 > 0);
  unsigned long long m2 = __ballot(v2 > 0);
  unsigned long long m3 = __ballot(v3 > 0);
  if ((t & 63) == 0) {
    size_t w = (size_t)n * (BROW / 2) + r * 16 + (t >> 6);
    bits[w] = m0;
    bits[w + 4] = m1;
    bits[w + 8] = m2;
    bits[w + 12] = m3;
  }
}

// ---------------- prep: W1 -> bf16 w1t[128][NNP]; cols 120..127 = f1/f2 features ----------------
__global__ __launch_bounds__(256) void k_prep(const float* __restrict__ W1,
                                              const float* __restrict__ a1s,
                                              const float* __restrict__ a1d,
                                              unsigned short* __restrict__ w1t) {
  int k = blockIdx.x * 256 + threadIdx.x;
#pragma unroll
  for (int h = 0; h < 4; ++h) {
    const float* wp = W1 + ((size_t)h * 4096 + k) * H1PER;
    float fs = 0.f, fd = 0.f;
#pragma unroll
    for (int oo = 0; oo < H1PER; ++oo) {
      float v = wp[oo];
      w1t[(size_t)(h * 30 + oo) * NNP + k] = bfrne(v);
      fs += v * a1s[h * H1PER + oo];
      fd += v * a1d[h * H1PER + oo];
    }
    w1t[(size_t)(120 + h) * NNP + k] = bfrne(fs);
    w1t[(size_t)(124 + h) * NNP + k] = bfrne(fd);
  }
}

// ---------------- MFMA GEMM1 (global_load_lds staging) ----------------
__global__ __launch_bounds__(256) void k_gemm1s(const float* __restrict__ x,
                                                const unsigned short* __restrict__ w1t,
                                                float* __restrict__ part) {
  const int t = threadIdx.x;
  const int lane = t & 63, wave = t >> 6;
  const int m = lane & 15, q = lane >> 4;
  const int i0 = blockIdx.x * 32;
  const int kz = blockIdx.y * 512;
  __shared__ float xs[32 * 64];
  const int r0 = (wave & 1) * 16;
  const int ntg0 = (wave >> 1) * 4;
  const int srow0 = wave * 8 + q;
  const int srow1 = srow0 + 4;
  const int sc0 = m ^ (srow0 & 7);
  const int sc1 = m ^ (srow1 & 7);
  const float* gx0 = x + (size_t)(i0 + srow0) * 4096 + kz + sc0 * 4;
  const float* gx1 = x + (size_t)(i0 + srow1) * 4096 + kz + sc1 * 4;
  float* ls0 = &xs[srow0 * 64 + m * 4];
  float* ls1 = &xs[srow1 * 64 + m * 4];
  const int arow = r0 + m;
  const int asw = (m & 7);
  f32x4 acc[4];
#pragma unroll
  for (int nt = 0; nt < 4; ++nt) acc[nt] = (f32x4){0.f, 0.f, 0.f, 0.f};
  for (int it = 0; it < 8; ++it) {
    const int kc = it * 64;
    GL16(gx0 + kc, ls0);
    GL16(gx1 + kc, ls1);
    __syncthreads();
#pragma unroll
    for (int ks2 = 0; ks2 < 2; ++ks2) {
      const int c0 = ks2 * 8 + q * 2;
      float4 a0 = *(const float4*)&xs[arow * 64 + ((c0 ^ asw) * 4)];
      float4 a1 = *(const float4*)&xs[arow * 64 + (((c0 + 1) ^ asw) * 4)];
      union { short8_t v; unsigned u[4]; } A;
      A.u[0] = bfpk_rne(a0.x, a0.y);
      A.u[1] = bfpk_rne(a0.z, a0.w);
      A.u[2] = bfpk_rne(a1.x, a1.y);
      A.u[3] = bfpk_rne(a1.z, a1.w);
      const unsigned short* wp = w1t + (size_t)m * NNP + kz + kc + ks2 * 32 + q * 8;
#pragma unroll
      for (int nt = 0; nt < 4; ++nt) {
        short8_t B = *(const short8_t*)(wp + (size_t)(ntg0 + nt) * 16 * NNP);
        acc[nt] = __builtin_amdgcn_mfma_f32_16x16x32_bf16(A.v, B, acc[nt], 0, 0, 0);
      }
    }
    __syncthreads();
  }
  float* pp = part + ((size_t)blockIdx.y * 4096 + i0 + r0 + q * 4) * 128 + ntg0 * 16 + m;
#pragma unroll
  for (int nt = 0; nt < 4; ++nt)
#pragma unroll
    for (int r = 0; r < 4; ++r) pp[r * 128 + nt * 16] = acc[nt][r];
}

// ---------------- combine 8 k-split partials -> whbt(bf16,T) + f1/f2 + max1(atomic) ----------------
__global__ __launch_bounds__(256) void k_f1c(const float* __restrict__ part,
                                             unsigned short* __restrict__ whbt,
                                             float* __restrict__ f1, float* __restrict__ f2,
                                             unsigned* __restrict__ mxu1) {
  const int t = threadIdx.x;
  const int n = blockIdx.x * 16 + (t >> 4);
  const int og = (t & 15) * 8;
  __shared__ float f2loc[16][4];
  float s[8] = {0.f, 0.f, 0.f, 0.f, 0.f, 0.f, 0.f, 0.f};
  for (int z = 0; z < 8; ++z) {
    const float* pp = part + ((size_t)z * NN + n) * 128 + og;
    float4 u0 = *(const float4*)pp;
    float4 u1 = *(const float4*)(pp + 4);
    s[0] += u0.x; s[1] += u0.y; s[2] += u0.z; s[3] += u0.w;
    s[4] += u1.x; s[5] += u1.y; s[6] += u1.z; s[7] += u1.w;
  }
  if (og < 120) {
#pragma unroll
    for (int j = 0; j < 8; ++j) {
      int o = og + j;
      int h = o / 30, oo = o - h * 30;
      whbt[(size_t)(h * 32 + oo) * NNP + n] = bfrne(s[j]);
    }
  } else {
#pragma unroll
    for (int j = 0; j < 4; ++j) {
      f1[(size_t)j * NN + n] = s[j];
      f2[(size_t)j * NN + n] = s[4 + j];
      f2loc[t >> 4][j] = s[4 + j];
    }
  }
  if ((t & 15) < 8) {
    int h = (t & 15) >> 1, odd = (t & 15) & 1;
    whbt[(size_t)(h * 32 + 30 + odd) * NNP + n] = odd ? 0 : 0x3f80;
  }
  __syncthreads();
  if (t < 4) {
    float m = f2loc[0][t];
#pragma unroll
    for (int i = 1; i < 16; ++i) m = fmaxf(m, f2loc[i][t]);
    atomicMax(&mxu1[t], fenc(m));
  }
}

// ---------------- MFMA attention layer 1 (exp-free; uint4 brow; padded strides) ----------------
// grid (64 i-blocks, 4 heads, 4 j-split), block 256
__global__ __launch_bounds__(256) void k_att1m(const unsigned short* __restrict__ whbt,
                                               const float* __restrict__ f1, const float* __restrict__ f2,
                                               const unsigned* __restrict__ mxu1,
                                               const unsigned int* __restrict__ bits32,
                                               float* __restrict__ part) {
  const int h = blockIdx.y, js = blockIdx.z;
  const int t = threadIdx.x;
  const int lane = t & 63, wave = t >> 6;
  const int m = lane & 15, q = lane >> 4;
  const int i0 = blockIdx.x * 64 + wave * 16;
  const int jbase = js * 1024;
  const float mxh = fdec(mxu1[h]);
  __shared__ float2 es[1024];
  for (int e = t; e < 1024; e += 256) {
    float fv = f2[h * NN + jbase + e] - mxh;
    es[e] = make_float2(__expf(fv), __expf(0.1f * fv));
  }
  __syncthreads();
  const float f1r = f1[h * NN + i0 + m];
  const float s = f1r + mxh;
  const float C1 = __expf(fminf(0.f, 0.9f * s));
  const float C2 = __expf(fminf(0.f, -0.9f * s));
  const float Tr = __expf(-s);
  const uint4* brow4 = (const uint4*)(bits32 + (size_t)(i0 + m) * BROW + (jbase >> 5));
  const unsigned short* bb0 = whbt + (size_t)(h * 32 + m) * NNP + jbase + q * 8;
  const unsigned short* bb1 = bb0 + 16 * NNP;
  const float2* fp = es + q * 8;
  f32x4 acc0 = {0.f, 0.f, 0.f, 0.f}, acc1 = {0.f, 0.f, 0.f, 0.f};
  for (int s4 = 0; s4 < 8; ++s4) {
    uint4 bq = brow4[s4];
#pragma unroll
    for (int sub = 0; sub < 4; ++sub) {
      const int step = s4 * 4 + sub;
      const int jl = step * 32;
      unsigned bsel = (sub == 0 ? bq.x : sub == 1 ? bq.y : sub == 2 ? bq.z : bq.w) >> (q * 8);
      float4 e01 = *(const float4*)(fp + jl);
      float4 e23 = *(const float4*)(fp + jl + 2);
      float4 e45 = *(const float4*)(fp + jl + 4);
      float4 e67 = *(const float4*)(fp + jl + 6);
      auto sc = [&](float ep, float en, int jj) {
        float wv = (ep > Tr) ? C1 * ep : C2 * en;
        return ((bsel >> jj) & 1u) ? wv : 0.f;
      };
      union { short8_t v; unsigned u[4]; } A;
      A.u[0] = bfpk(sc(e01.x, e01.y, 0), sc(e01.z, e01.w, 1));
      A.u[1] = bfpk(sc(e23.x, e23.y, 2), sc(e23.z, e23.w, 3));
      A.u[2] = bfpk(sc(e45.x, e45.y, 4), sc(e45.z, e45.w, 5));
      A.u[3] = bfpk(sc(e67.x, e67.y, 6), sc(e67.z, e67.w, 7));
      short8_t b0 = *(const short8_t*)(bb0 + jl);
      short8_t b1 = *(const short8_t*)(bb1 + jl);
      acc0 = __builtin_amdgcn_mfma_f32_16x16x32_bf16(A.v, b0, acc0, 0, 0, 0);
      acc1 = __builtin_amdgcn_mfma_f32_16x16x32_bf16(A.v, b1, acc1, 0, 0, 0);
    }
  }
  float* pp = part + ((size_t)(js * 4 + h) * NN + i0 + q * 4) * 32 + m;
#pragma unroll
  for (int r = 0; r < 4; ++r) {
    pp[r * 32] = acc0[r];
    pp[r * 32 + 16] = acc1[r];
  }
}

// ---------------- fused: h1 combine + GEMM2 + f2/whbt2 + max2 ----------------
// grid 1024, block 256 (4 waves = 4 nodes)
__global__ __launch_bounds__(256) void k_fuseA(const float* __restrict__ part, const float* __restrict__ b1,
                                               const float* __restrict__ W2, const float* __restrict__ a2s,
                                               const float* __restrict__ a2d,
                                               unsigned short* __restrict__ whbt2,
                                               float* __restrict__ f1b, float* __restrict__ f2b,
                                               unsigned* __restrict__ mxu2) {
  const int t = threadIdx.x;
  __shared__ float W2s[H1DIM * H2DIM];
  __shared__ float h1s[4][124];
  __shared__ float f2red[4];
  for (int e = t; e < H1DIM * H2DIM; e += 256) W2s[e] = W2[e];
  const int wv = t >> 6, lane = t & 63;
  const int n = blockIdx.x * 4 + wv;
  const int h = lane >> 4, o2 = (lane & 15) * 2;
  float tot0 = 0.f, tot1 = 0.f;
#pragma unroll
  for (int z = 0; z < 4; ++z) {
    const float* pp = part + ((size_t)(z * 4 + h) * NN + n) * 32 + o2;
    float2 u = *(const float2*)pp;
    tot0 += u.x;
    tot1 += u.y;
  }
  float l = __shfl(tot0, h * 16 + 15);
  float inv = 1.f / l;
  if (o2 < 30) {
    h1s[wv][h * 30 + o2] = lrelu(tot0 * inv + b1[h * 30 + o2]);
    h1s[wv][h * 30 + o2 + 1] = lrelu(tot1 * inv + b1[h * 30 + o2 + 1]);
  }
  __syncthreads();
  const int o = lane;
  float acc = 0.f;
  if (o < H2DIM) {
    const float* hr = h1s[wv];
#pragma unroll 4
    for (int k = 0; k < H1DIM; ++k) acc += hr[k] * W2s[k * H2DIM + o];
  }
  unsigned short wbv = (o < H2DIM) ? bfrne(acc) : (o == H2DIM ? (unsigned short)0x3f80 : (unsigned short)0);
  whbt2[(size_t)o * NNP + n] = wbv;
  float ps = (o < H2DIM) ? acc * a2s[o] : 0.f;
  float pd = (o < H2DIM) ? acc * a2d[o] : 0.f;
  for (int off = 32; off > 0; off >>= 1) {
    ps += __shfl_down(ps, off);
    pd += __shfl_down(pd, off);
  }
  if (lane == 0) {
    f1b[n] = ps;
    f2b[n] = pd;
    f2red[wv] = pd;
  }
  __syncthreads();
  if (t == 0) {
    float m = fmaxf(fmaxf(f2red[0], f2red[1]), fmaxf(f2red[2], f2red[3]));
    atomicMax(mxu2, fenc(m));
  }
}

// ---------------- MFMA attention layer 2 (exp-free; uint4 brow; padded strides) ----------------
// grid (64 i-blocks, 8 j-split), block 256
__global__ __launch_bounds__(256) void k_att2m(const unsigned short* __restrict__ whbt2,
                                               const float* __restrict__ f1b, const float* __restrict__ f2b,
                                               const unsigned* __restrict__ mxu2,
                                               const unsigned int* __restrict__ bits32,
                                               float* __restrict__ part) {
  const int js = blockIdx.y;
  const int t = threadIdx.x;
  const int lane = t & 63, wave = t >> 6;
  const int m = lane & 15, q = lane >> 4;
  const int i0 = blockIdx.x * 64 + wave * 16;
  const int jbase = js * 512;
  const float mx0 = fdec(mxu2[0]);
  __shared__ float2 es[512];
  for (int e = t; e < 512; e += 256) {
    float fv = f2b[jbase + e] - mx0;
    es[e] = make_float2(__expf(fv), __expf(0.1f * fv));
  }
  __syncthreads();
  const float f1r = f1b[i0 + m];
  const float s = f1r + mx0;
  const float C1 = __expf(fminf(0.f, 0.9f * s));
  const float C2 = __expf(fminf(0.f, -0.9f * s));
  const float Tr = __expf(-s);
  const uint4* brow4 = (const uint4*)(bits32 + (size_t)(i0 + m) * BROW + (jbase >> 5));
  const unsigned short* bb = whbt2 + (size_t)m * NNP + jbase + q * 8;
  const float2* fp = es + q * 8;
  f32x4 acc[4];
#pragma unroll
  for (int x = 0; x < 4; ++x) acc[x] = (f32x4){0.f, 0.f, 0.f, 0.f};
  for (int s4 = 0; s4 < 4; ++s4) {
    uint4 bq = brow4[s4];
#pragma unroll
    for (int sub = 0; sub < 4; ++sub) {
      const int step = s4 * 4 + sub;
      const int jl = step * 32;
      unsigned bsel = (sub == 0 ? bq.x : sub == 1 ? bq.y : sub == 2 ? bq.z : bq.w) >> (q * 8);
      float4 e01 = *(const float4*)(fp + jl);
      float4 e23 = *(const float4*)(fp + jl + 2);
      float4 e45 = *(const float4*)(fp + jl + 4);
      float4 e67 = *(const float4*)(fp + jl + 6);
      auto sc = [&](float ep, float en, int jj) {
        float wv = (ep > Tr) ? C1 * ep : C2 * en;
        return ((bsel >> jj) & 1u) ? wv : 0.f;
      };
      union { short8_t v; unsigned u[4]; } A;
      A.u[0] = bfpk(sc(e01.x, e01.y, 0), sc(e01.z, e01.w, 1));
      A.u[1] = bfpk(sc(e23.x, e23.y, 2), sc(e23.z, e23.w, 3));
      A.u[2] = bfpk(sc(e45.x, e45.y, 4), sc(e45.z, e45.w, 5));
      A.u[3] = bfpk(sc(e67.x, e67.y, 6), sc(e67.z, e67.w, 7));
#pragma unroll
      for (int tile = 0; tile < 4; ++tile) {
        short8_t b = *(const short8_t*)(bb + (size_t)tile * 16 * NNP + jl);
        acc[tile] = __builtin_amdgcn_mfma_f32_16x16x32_bf16(A.v, b, acc[tile], 0, 0, 0);
      }
    }
  }
  float* pp = part + ((size_t)js * NN + i0 + q * 4) * 64 + m;
#pragma unroll
  for (int tile = 0; tile < 4; ++tile)
#pragma unroll
    for (int r = 0; r < 4; ++r) pp[r * 64 + tile * 16] = acc[tile][r];
}

// ---------------- fused: h2 combine + FiLM + logits ----------------
// grid 1024, block 256 (4 waves = 4 nodes)
__global__ __launch_bounds__(256) void k_fuseB(const float* __restrict__ part, const float* __restrict__ b2,
                                               const float* __restrict__ l_loc,
                                               const float* __restrict__ Wl1, const float* __restrict__ bl1,
                                               const float* __restrict__ Wl2, const float* __restrict__ bl2,
                                               const float* __restrict__ Wg, const float* __restrict__ bg,
                                               const float* __restrict__ Wb, const float* __restrict__ bb,
                                               const float* __restrict__ Wgate, const float* __restrict__ bgate,
                                               const float* __restrict__ Wc, float* __restrict__ logits) {
  const int t = threadIdx.x;
  const int wv = t >> 6, lane = t & 63;
  const int n = blockIdx.x * 4 + wv;
  const float* p = part + (size_t)n * 64 + lane;
  float tot = 0.f;
#pragma unroll
  for (int z = 0; z < 8; ++z) tot += p[(size_t)z * NN * 64];
  float l = __shfl(tot, 50);
  float hv = (lane < H2DIM) ? lrelu(tot / l + b2[lane]) : 0.f;
  // FiLM
  int r32 = lane & 31;
  float locv = l_loc[n * 16 + (lane & 15)];
  float cov = __shfl(locv, 15);
  cov = fminf(fmaxf(cov, 0.f), 1.f);
  float a1v = bl1[r32];
#pragma unroll
  for (int j = 0; j < 16; ++j) a1v += Wl1[r32 * 16 + j] * __shfl(locv, j);
  float z1 = lrelu(a1v);
  float a2v = bl2[r32];
#pragma unroll
  for (int j = 0; j < 32; ++j) a2v += Wl2[r32 * 32 + j] * __shfl(z1, j);
  float z2 = lrelu(a2v);
  float gs = bgate[0];
  float gam, bet;
  {
    int o = lane < H2DIM ? lane : 0;
    gam = bg[o];
    bet = bb[o];
#pragma unroll
    for (int j = 0; j < 32; ++j) {
      float zj = __shfl(z2, j);
      gs += Wgate[j] * zj;
      gam += Wg[o * 32 + j] * zj;
      bet += Wb[o * 32 + j] * zj;
    }
  }
  float g = cov / (1.f + __expf(-gs));
  float hf = hv + g * (gam * hv + bet);
  int o = lane < H2DIM ? lane : 0;
  float p0 = lane < H2DIM ? hf * Wc[o] : 0.f;
  float p1 = lane < H2DIM ? hf * Wc[H2DIM + o] : 0.f;
  for (int off = 32; off > 0; off >>= 1) {
    p0 += __shfl_down(p0, off);
    p1 += __shfl_down(p1, off);
  }
  if (lane == 0) {
    logits[n * 2 + 0] = lrelu(p0);
    logits[n * 2 + 1] = lrelu(p1);
  }
}

// ---------------- fused SSDB: hsum + B + final output (single block, 1024 thr) ----------------
__global__ __launch_bounds__(1024) void k_ssdb(const float* __restrict__ logits,
                                               const float* __restrict__ Ws1, const float* __restrict__ bs1,
                                               const float* __restrict__ Ws2, const float* __restrict__ bs2,
                                               float* __restrict__ out) {
  const int t = threadIdx.x;
  __shared__ float lg[8192];
  __shared__ float hs[256];
  __shared__ float Bs[4];
  for (int e = t; e < 8192; e += 1024) lg[e] = logits[e];
  __syncthreads();
  if (t < 960) {
    int item = t >> 2, seg = t & 3;  // item = combo*60 + k
    int k = item % 60, combo = item / 60;
    int hemi = combo >> 1, c = combo & 1;
    const float* wr = Ws1 + (size_t)k * 2048 + seg * 512;
    const float* lc = logits + (size_t)(hemi * 2048 + seg * 512) * 2 + c;
    float pacc = 0.f;
    for (int q2 = 0; q2 < 512; ++q2) pacc += wr[q2] * lc[2 * q2];
    pacc += __shfl_down(pacc, 1);
    pacc += __shfl_down(pacc, 2);
    if (seg == 0) hs[item] = pacc;
  }
  __syncthreads();
  if (t < 256) {
    int combo = t >> 6, k2 = t & 63;
    float v = (k2 < 60) ? lrelu(hs[combo * 60 + k2] + bs1[k2]) * Ws2[k2] : 0.f;
    for (int off = 32; off > 0; off >>= 1) v += __shfl_down(v, off);
    if (k2 == 0) Bs[combo] = lrelu(v + bs2[0]);
  }
  __syncthreads();
  for (int e = t; e < 8192; e += 1024) {
    int nn = e >> 1, c = e & 1;
    out[e] = lg[e] + Bs[(nn < 2048 ? 0 : 2) + c];
  }
  if (t == 0) out[8192] = 0.5f * (Bs[0] + Bs[2]);
  if (t == 1) out[8193] = 0.5f * (Bs[1] + Bs[3]);
}

// ---------------- workspace layout (float offsets) ----------------
#define OFF_BITS 0          // 4096*66 u64 = 540672 f
#define OFF_W1T 540672      // 128*4128 shorts = 264192 f
#define OFF_GP 804864       // [8][4096][128] = 4194304 f; A1P/A2P overlay
#define OFF_A1P 804864      // [4][4][4096][32] = 2097152
#define OFF_A2P 804864      // [8][4096][64] = 2097152
#define OFF_WH1BT 4999168   // 128*4128 shorts = 264192 f
#define OFF_F1A 5263360     // [4][4096]
#define OFF_F2A 5279744     // [4][4096]
#define OFF_WH2BT 5296128   // 64*4128 shorts = 132096 f
#define OFF_F12 5428224     // 4096
#define OFF_F22 5432320     // 4096
#define OFF_LOG 5436416     // 8192
#define OFF_MX 5444608      // 8 uints: [0..3]=mxu1, [4]=mxu2

extern "C" void kernel_launch(void* const* d_in, const int* in_sizes, int n_in,
                              void* d_out, int out_size, void* d_ws, size_t ws_size,
                              hipStream_t stream) {
  const float* x_fc  = (const float*)d_in[0];
  const int*   adj   = (const int*)d_in[1];
  const float* l_loc = (const float*)d_in[2];
  const float* W1    = (const float*)d_in[3];
  const float* a1s   = (const float*)d_in[4];
  const float* a1d   = (const float*)d_in[5];
  const float* b1    = (const float*)d_in[6];
  const float* W2    = (const float*)d_in[7];
  const float* a2s   = (const float*)d_in[8];
  const float* a2d   = (const float*)d_in[9];
  const float* b2    = (const float*)d_in[10];
  const float* Wc    = (const float*)d_in[11];
  const float* Wl1   = (const float*)d_in[12];
  const float* bl1   = (const float*)d_in[13];
  const float* Wl2   = (const float*)d_in[14];
  const float* bl2   = (const float*)d_in[15];
  const float* Wg    = (const float*)d_in[16];
  const float* bg    = (const float*)d_in[17];
  const float* Wb    = (const float*)d_in[18];
  const float* bb    = (const float*)d_in[19];
  const float* Wgate = (const float*)d_in[20];
  const float* bgate = (const float*)d_in[21];
  const float* Ws1   = (const float*)d_in[22];
  const float* bs1   = (const float*)d_in[23];
  const float* Ws2   = (const float*)d_in[24];
  const float* bs2   = (const float*)d_in[25];
  float* out = (float*)d_out;
  float* w = (float*)d_ws;
  unsigned long long* bits = (unsigned long long*)(w + OFF_BITS);
  const unsigned int* bits32 = (const unsigned int*)bits;
  unsigned short* wh1bt = (unsigned short*)(w + OFF_WH1BT);
  unsigned short* wh2bt = (unsigned short*)(w + OFF_WH2BT);
  unsigned short* w1t = (unsigned short*)(w + OFF_W1T);
  unsigned* mxu = (unsigned*)(w + OFF_MX);

  hipMemsetAsync(mxu, 0, 8 * sizeof(unsigned), stream);  // encoded-domain minimum
  k_bits<<<NN * NN / 1024, 256, 0, stream>>>(adj, bits);
  k_prep<<<16, 256, 0, stream>>>(W1, a1s, a1d, w1t);
  k_gemm1s<<<dim3(128, 8), 256, 0, stream>>>(x_fc, w1t, w + OFF_GP);
  k_f1c<<<256, 256, 0, stream>>>(w + OFF_GP, wh1bt, w + OFF_F1A, w + OFF_F2A, mxu);
  k_att1m<<<dim3(64, HEADS, 4), 256, 0, stream>>>(wh1bt, w + OFF_F1A, w + OFF_F2A,
                                                  mxu, bits32, w + OFF_A1P);
  k_fuseA<<<1024, 256, 0, stream>>>(w + OFF_A1P, b1, W2, a2s, a2d, wh2bt,
                                    w + OFF_F12, w + OFF_F22, mxu + 4);
  k_att2m<<<dim3(64, 8), 256, 0, stream>>>(wh2bt, w + OFF_F12, w + OFF_F22,
                                           mxu + 4, bits32, w + OFF_A2P);
  k_fuseB<<<1024, 256, 0, stream>>>(w + OFF_A2P, b2, l_loc, Wl1, bl1, Wl2, bl2,
                                    Wg, bg, Wb, bb, Wgate, bgate, Wc, w + OFF_LOG);
  k_ssdb<<<1, 1024, 0, stream>>>(w + OFF_LOG, Ws1, bs1, Ws2, bs2, out);
}

// Round 10
// 322.228 us; speedup vs baseline: 1.3176x; 1.3176x over previous
//
#include <hip/hip_runtime.h>

#define NN 4096
#define NNP 4128   // padded row stride (shorts) to break 8KB channel aliasing
#define BROW 132   // bits row stride in u32 (528B, breaks 512B aliasing)
#define HEADS 4
#define H1PER 30
#define H1DIM 120
#define H2DIM 50

typedef short short8_t __attribute__((ext_vector_type(8)));
typedef float f32x4 __attribute__((ext_vector_type(4)));

__device__ __forceinline__ float lrelu(float x) { return x > 0.f ? x : 0.1f * x; }

__device__ __forceinline__ unsigned short bfrne(float x) {
  unsigned u = __float_as_uint(x);
  u += 0x7fffu + ((u >> 16) & 1u);
  return (unsigned short)(u >> 16);
}
__device__ __forceinline__ unsigned bfpk_rne(float lo, float hi) {
  return (unsigned)bfrne(lo) | ((unsigned)bfrne(hi) << 16);
}
__device__ __forceinline__ unsigned bfpk(float lo, float hi) {
  unsigned a = (__float_as_uint(lo) + 0x8000u) >> 16;
  unsigned b = (__float_as_uint(hi) + 0x8000u) & 0xffff0000u;
  return a | b;
}
// monotone float<->uint encoding for atomicMax-based float max
__device__ __forceinline__ unsigned fenc(float x) {
  unsigned u = __float_as_uint(x);
  return (u & 0x80000000u) ? ~u : (u | 0x80000000u);
}
__device__ __forceinline__ float fdec(unsigned u) {
  return (u & 0x80000000u) ? __uint_as_float(u ^ 0x80000000u) : __uint_as_float(~u);
}

#define GL16(g, l)                                                                        \
  __builtin_amdgcn_global_load_lds((const __attribute__((address_space(1))) unsigned int*)(g), \
                                   (__attribute__((address_space(3))) unsigned int*)(l), 16, 0, 0)

// ---------------- bitmask: adj(int32) -> 1 bit, padded rows ----------------
__global__ __launch_bounds__(256) void k_bits(const int* __restrict__ adj,
                                              unsigned long long* __restrict__ bits) {
  int n = blockIdx.x >> 2, r = blockIdx.x & 3;
  size_t base = (size_t)n * 4096 + r * 1024;
  int t = threadIdx.x;
  int v0 = adj[base + t];
  int v1 = adj[base + 256 + t];
  int v2 = adj[base + 512 + t];
  int v3 = adj[base + 768 + t];
  unsigned long long m0 = __ballot(v0 > 0);
  unsigned long long m1 = __ballot(v1 > 0);
  unsigned long long m2 = __ballot(v2 > 0);
  unsigned long long m3 = __ballot(v3 > 0);
  if ((t & 63) == 0) {
    size_t w = (size_t)n * (BROW / 2) + r * 16 + (t >> 6);
    bits[w] = m0;
    bits[w + 4] = m1;
    bits[w + 8] = m2;
    bits[w + 12] = m3;
  }
}

// ---------------- prep: W1 -> bf16 w1t[128][NNP]; cols 120..127 = f1/f2 features ----------------
__global__ __launch_bounds__(256) void k_prep(const float* __restrict__ W1,
                                              const float* __restrict__ a1s,
                                              const float* __restrict__ a1d,
                                              unsigned short* __restrict__ w1t) {
  int k = blockIdx.x * 256 + threadIdx.x;
#pragma unroll
  for (int h = 0; h < 4; ++h) {
    const float* wp = W1 + ((size_t)h * 4096 + k) * H1PER;
    float fs = 0.f, fd = 0.f;
#pragma unroll
    for (int oo = 0; oo < H1PER; ++oo) {
      float v = wp[oo];
      w1t[(size_t)(h * 30 + oo) * NNP + k] = bfrne(v);
      fs += v * a1s[h * H1PER + oo];
      fd += v * a1d[h * H1PER + oo];
    }
    w1t[(size_t)(120 + h) * NNP + k] = bfrne(fs);
    w1t[(size_t)(124 + h) * NNP + k] = bfrne(fd);
  }
}

// ---------------- MFMA GEMM1 (global_load_lds staging) ----------------
__global__ __launch_bounds__(256) void k_gemm1s(const float* __restrict__ x,
                                                const unsigned short* __restrict__ w1t,
                                                float* __restrict__ part) {
  const int t = threadIdx.x;
  const int lane = t & 63, wave = t >> 6;
  const int m = lane & 15, q = lane >> 4;
  const int i0 = blockIdx.x * 32;
  const int kz = blockIdx.y * 512;
  __shared__ float xs[32 * 64];
  const int r0 = (wave & 1) * 16;
  const int ntg0 = (wave >> 1) * 4;
  const int srow0 = wave * 8 + q;
  const int srow1 = srow0 + 4;
  const int sc0 = m ^ (srow0 & 7);
  const int sc1 = m ^ (srow1 & 7);
  const float* gx0 = x + (size_t)(i0 + srow0) * 4096 + kz + sc0 * 4;
  const float* gx1 = x + (size_t)(i0 + srow1) * 4096 + kz + sc1 * 4;
  float* ls0 = &xs[srow0 * 64 + m * 4];
  float* ls1 = &xs[srow1 * 64 + m * 4];
  const int arow = r0 + m;
  const int asw = (m & 7);
  f32x4 acc[4];
#pragma unroll
  for (int nt = 0; nt < 4; ++nt) acc[nt] = (f32x4){0.f, 0.f, 0.f, 0.f};
  for (int it = 0; it < 8; ++it) {
    const int kc = it * 64;
    GL16(gx0 + kc, ls0);
    GL16(gx1 + kc, ls1);
    __syncthreads();
#pragma unroll
    for (int ks2 = 0; ks2 < 2; ++ks2) {
      const int c0 = ks2 * 8 + q * 2;
      float4 a0 = *(const float4*)&xs[arow * 64 + ((c0 ^ asw) * 4)];
      float4 a1 = *(const float4*)&xs[arow * 64 + (((c0 + 1) ^ asw) * 4)];
      union { short8_t v; unsigned u[4]; } A;
      A.u[0] = bfpk_rne(a0.x, a0.y);
      A.u[1] = bfpk_rne(a0.z, a0.w);
      A.u[2] = bfpk_rne(a1.x, a1.y);
      A.u[3] = bfpk_rne(a1.z, a1.w);
      const unsigned short* wp = w1t + (size_t)m * NNP + kz + kc + ks2 * 32 + q * 8;
#pragma unroll
      for (int nt = 0; nt < 4; ++nt) {
        short8_t B = *(const short8_t*)(wp + (size_t)(ntg0 + nt) * 16 * NNP);
        acc[nt] = __builtin_amdgcn_mfma_f32_16x16x32_bf16(A.v, B, acc[nt], 0, 0, 0);
      }
    }
    __syncthreads();
  }
  float* pp = part + ((size_t)blockIdx.y * 4096 + i0 + r0 + q * 4) * 128 + ntg0 * 16 + m;
#pragma unroll
  for (int nt = 0; nt < 4; ++nt)
#pragma unroll
    for (int r = 0; r < 4; ++r) pp[r * 128 + nt * 16] = acc[nt][r];
}

// ---------------- combine 8 k-split partials -> whbt(bf16,T) + f1/f2 + max1(atomic) ----------------
__global__ __launch_bounds__(256) void k_f1c(const float* __restrict__ part,
                                             unsigned short* __restrict__ whbt,
                                             float* __restrict__ f1, float* __restrict__ f2,
                                             unsigned* __restrict__ mxu1) {
  const int t = threadIdx.x;
  const int n = blockIdx.x * 16 + (t >> 4);
  const int og = (t & 15) * 8;
  __shared__ float f2loc[16][4];
  float s[8] = {0.f, 0.f, 0.f, 0.f, 0.f, 0.f, 0.f, 0.f};
  for (int z = 0; z < 8; ++z) {
    const float* pp = part + ((size_t)z * NN + n) * 128 + og;
    float4 u0 = *(const float4*)pp;
    float4 u1 = *(const float4*)(pp + 4);
    s[0] += u0.x; s[1] += u0.y; s[2] += u0.z; s[3] += u0.w;
    s[4] += u1.x; s[5] += u1.y; s[6] += u1.z; s[7] += u1.w;
  }
  if (og < 120) {
#pragma unroll
    for (int j = 0; j < 8; ++j) {
      int o = og + j;
      int h = o / 30, oo = o - h * 30;
      whbt[(size_t)(h * 32 + oo) * NNP + n] = bfrne(s[j]);
    }
  } else {
#pragma unroll
    for (int j = 0; j < 4; ++j) {
      f1[(size_t)j * NN + n] = s[j];
      f2[(size_t)j * NN + n] = s[4 + j];
      f2loc[t >> 4][j] = s[4 + j];
    }
  }
  if ((t & 15) < 8) {
    int h = (t & 15) >> 1, odd = (t & 15) & 1;
    whbt[(size_t)(h * 32 + 30 + odd) * NNP + n] = odd ? 0 : 0x3f80;
  }
  __syncthreads();
  if (t < 4) {
    float m = f2loc[0][t];
#pragma unroll
    for (int i = 1; i < 16; ++i) m = fmaxf(m, f2loc[i][t]);
    atomicMax(&mxu1[t], fenc(m));
  }
}

// ---------------- MFMA attention layer 1 (exp-free; uint4 brow; padded strides) ----------------
// grid (64 i-blocks, 4 heads, 4 j-split), block 256
__global__ __launch_bounds__(256) void k_att1m(const unsigned short* __restrict__ whbt,
                                               const float* __restrict__ f1, const float* __restrict__ f2,
                                               const unsigned* __restrict__ mxu1,
                                               const unsigned int* __restrict__ bits32,
                                               float* __restrict__ part) {
  const int h = blockIdx.y, js = blockIdx.z;
  const int t = threadIdx.x;
  const int lane = t & 63, wave = t >> 6;
  const int m = lane & 15, q = lane >> 4;
  const int i0 = blockIdx.x * 64 + wave * 16;
  const int jbase = js * 1024;
  const float mxh = fdec(mxu1[h]);
  __shared__ float2 es[1024];
  for (int e = t; e < 1024; e += 256) {
    float fv = f2[h * NN + jbase + e] - mxh;
    es[e] = make_float2(__expf(fv), __expf(0.1f * fv));
  }
  __syncthreads();
  const float f1r = f1[h * NN + i0 + m];
  const float s = f1r + mxh;
  const float C1 = __expf(fminf(0.f, 0.9f * s));
  const float C2 = __expf(fminf(0.f, -0.9f * s));
  const float Tr = __expf(-s);
  const uint4* brow4 = (const uint4*)(bits32 + (size_t)(i0 + m) * BROW + (jbase >> 5));
  const unsigned short* bb0 = whbt + (size_t)(h * 32 + m) * NNP + jbase + q * 8;
  const unsigned short* bb1 = bb0 + 16 * NNP;
  const float2* fp = es + q * 8;
  f32x4 acc0 = {0.f, 0.f, 0.f, 0.f}, acc1 = {0.f, 0.f, 0.f, 0.f};
  for (int s4 = 0; s4 < 8; ++s4) {
    uint4 bq = brow4[s4];
#pragma unroll
    for (int sub = 0; sub < 4; ++sub) {
      const int step = s4 * 4 + sub;
      const int jl = step * 32;
      unsigned bsel = (sub == 0 ? bq.x : sub == 1 ? bq.y : sub == 2 ? bq.z : bq.w) >> (q * 8);
      float4 e01 = *(const float4*)(fp + jl);
      float4 e23 = *(const float4*)(fp + jl + 2);
      float4 e45 = *(const float4*)(fp + jl + 4);
      float4 e67 = *(const float4*)(fp + jl + 6);
      auto sc = [&](float ep, float en, int jj) {
        float wv = (ep > Tr) ? C1 * ep : C2 * en;
        return ((bsel >> jj) & 1u) ? wv : 0.f;
      };
      union { short8_t v; unsigned u[4]; } A;
      A.u[0] = bfpk(sc(e01.x, e01.y, 0), sc(e01.z, e01.w, 1));
      A.u[1] = bfpk(sc(e23.x, e23.y, 2), sc(e23.z, e23.w, 3));
      A.u[2] = bfpk(sc(e45.x, e45.y, 4), sc(e45.z, e45.w, 5));
      A.u[3] = bfpk(sc(e67.x, e67.y, 6), sc(e67.z, e67.w, 7));
      short8_t b0 = *(const short8_t*)(bb0 + jl);
      short8_t b1 = *(const short8_t*)(bb1 + jl);
      acc0 = __builtin_amdgcn_mfma_f32_16x16x32_bf16(A.v, b0, acc0, 0, 0, 0);
      acc1 = __builtin_amdgcn_mfma_f32_16x16x32_bf16(A.v, b1, acc1, 0, 0, 0);
    }
  }
  float* pp = part + ((size_t)(js * 4 + h) * NN + i0 + q * 4) * 32 + m;
#pragma unroll
  for (int r = 0; r < 4; ++r) {
    pp[r * 32] = acc0[r];
    pp[r * 32 + 16] = acc1[r];
  }
}

// ---------------- fused: h1 combine + GEMM2 + f2/whbt2 + max2 ----------------
// grid 1024, block 256 (4 waves = 4 nodes)
__global__ __launch_bounds__(256) void k_fuseA(const float* __restrict__ part, const float* __restrict__ b1,
                                               const float* __restrict__ W2, const float* __restrict__ a2s,
                                               const float* __restrict__ a2d,
                                               unsigned short* __restrict__ whbt2,
                                               float* __restrict__ f1b, float* __restrict__ f2b,
                                               unsigned* __restrict__ mxu2) {
  const int t = threadIdx.x;
  __shared__ float W2s[H1DIM * H2DIM];
  __shared__ float h1s[4][124];
  __shared__ float f2red[4];
  for (int e = t; e < H1DIM * H2DIM; e += 256) W2s[e] = W2[e];
  const int wv = t >> 6, lane = t & 63;
  const int n = blockIdx.x * 4 + wv;
  const int h = lane >> 4, o2 = (lane & 15) * 2;
  float tot0 = 0.f, tot1 = 0.f;
#pragma unroll
  for (int z = 0; z < 4; ++z) {
    const float* pp = part + ((size_t)(z * 4 + h) * NN + n) * 32 + o2;
    float2 u = *(const float2*)pp;
    tot0 += u.x;
    tot1 += u.y;
  }
  float l = __shfl(tot0, h * 16 + 15);
  float inv = 1.f / l;
  if (o2 < 30) {
    h1s[wv][h * 30 + o2] = lrelu(tot0 * inv + b1[h * 30 + o2]);
    h1s[wv][h * 30 + o2 + 1] = lrelu(tot1 * inv + b1[h * 30 + o2 + 1]);
  }
  __syncthreads();
  const int o = lane;
  float acc = 0.f;
  if (o < H2DIM) {
    const float* hr = h1s[wv];
#pragma unroll 4
    for (int k = 0; k < H1DIM; ++k) acc += hr[k] * W2s[k * H2DIM + o];
  }
  unsigned short wbv = (o < H2DIM) ? bfrne(acc) : (o == H2DIM ? (unsigned short)0x3f80 : (unsigned short)0);
  whbt2[(size_t)o * NNP + n] = wbv;
  float ps = (o < H2DIM) ? acc * a2s[o] : 0.f;
  float pd = (o < H2DIM) ? acc * a2d[o] : 0.f;
  for (int off = 32; off > 0; off >>= 1) {
    ps += __shfl_down(ps, off);
    pd += __shfl_down(pd, off);
  }
  if (lane == 0) {
    f1b[n] = ps;
    f2b[n] = pd;
    f2red[wv] = pd;
  }
  __syncthreads();
  if (t == 0) {
    float m = fmaxf(fmaxf(f2red[0], f2red[1]), fmaxf(f2red[2], f2red[3]));
    atomicMax(mxu2, fenc(m));
  }
}

// ---------------- MFMA attention layer 2 (exp-free; uint4 brow; padded strides) ----------------
// grid (64 i-blocks, 8 j-split), block 256
__global__ __launch_bounds__(256) void k_att2m(const unsigned short* __restrict__ whbt2,
                                               const float* __restrict__ f1b, const float* __restrict__ f2b,
                                               const unsigned* __restrict__ mxu2,
                                               const unsigned int* __restrict__ bits32,
                                               float* __restrict__ part) {
  const int js = blockIdx.y;
  const int t = threadIdx.x;
  const int lane = t & 63, wave = t >> 6;
  const int m = lane & 15, q = lane >> 4;
  const int i0 = blockIdx.x * 64 + wave * 16;
  const int jbase = js * 512;
  const float mx0 = fdec(mxu2[0]);
  __shared__ float2 es[512];
  for (int e = t; e < 512; e += 256) {
    float fv = f2b[jbase + e] - mx0;
    es[e] = make_float2(__expf(fv), __expf(0.1f * fv));
  }
  __syncthreads();
  const float f1r = f1b[i0 + m];
  const float s = f1r + mx0;
  const float C1 = __expf(fminf(0.f, 0.9f * s));
  const float C2 = __expf(fminf(0.f, -0.9f * s));
  const float Tr = __expf(-s);
  const uint4* brow4 = (const uint4*)(bits32 + (size_t)(i0 + m) * BROW + (jbase >> 5));
  const unsigned short* bb = whbt2 + (size_t)m * NNP + jbase + q * 8;
  const float2* fp = es + q * 8;
  f32x4 acc[4];
#pragma unroll
  for (int x = 0; x < 4; ++x) acc[x] = (f32x4){0.f, 0.f, 0.f, 0.f};
  for (int s4 = 0; s4 < 4; ++s4) {
    uint4 bq = brow4[s4];
#pragma unroll
    for (int sub = 0; sub < 4; ++sub) {
      const int step = s4 * 4 + sub;
      const int jl = step * 32;
      unsigned bsel = (sub == 0 ? bq.x : sub == 1 ? bq.y : sub == 2 ? bq.z : bq.w) >> (q * 8);
      float4 e01 = *(const float4*)(fp + jl);
      float4 e23 = *(const float4*)(fp + jl + 2);
      float4 e45 = *(const float4*)(fp + jl + 4);
      float4 e67 = *(const float4*)(fp + jl + 6);
      auto sc = [&](float ep, float en, int jj) {
        float wv = (ep > Tr) ? C1 * ep : C2 * en;
        return ((bsel >> jj) & 1u) ? wv : 0.f;
      };
      union { short8_t v; unsigned u[4]; } A;
      A.u[0] = bfpk(sc(e01.x, e01.y, 0), sc(e01.z, e01.w, 1));
      A.u[1] = bfpk(sc(e23.x, e23.y, 2), sc(e23.z, e23.w, 3));
      A.u[2] = bfpk(sc(e45.x, e45.y, 4), sc(e45.z, e45.w, 5));
      A.u[3] = bfpk(sc(e67.x, e67.y, 6), sc(e67.z, e67.w, 7));
#pragma unroll
      for (int tile = 0; tile < 4; ++tile) {
        short8_t b = *(const short8_t*)(bb + (size_t)tile * 16 * NNP + jl);
        acc[tile] = __builtin_amdgcn_mfma_f32_16x16x32_bf16(A.v, b, acc[tile], 0, 0, 0);
      }
    }
  }
  float* pp = part + ((size_t)js * NN + i0 + q * 4) * 64 + m;
#pragma unroll
  for (int tile = 0; tile < 4; ++tile)
#pragma unroll
    for (int r = 0; r < 4; ++r) pp[r * 64 + tile * 16] = acc[tile][r];
}

// ---------------- fused: h2 combine + FiLM + logits ----------------
// grid 1024, block 256 (4 waves = 4 nodes)
__global__ __launch_bounds__(256) void k_fuseB(const float* __restrict__ part, const float* __restrict__ b2,
                                               const float* __restrict__ l_loc,
                                               const float* __restrict__ Wl1, const float* __restrict__ bl1,
                                               const float* __restrict__ Wl2, const float* __restrict__ bl2,
                                               const float* __restrict__ Wg, const float* __restrict__ bg,
                                               const float* __restrict__ Wb, const float* __restrict__ bb,
                                               const float* __restrict__ Wgate, const float* __restrict__ bgate,
                                               const float* __restrict__ Wc, float* __restrict__ logits) {
  const int t = threadIdx.x;
  const int wv = t >> 6, lane = t & 63;
  const int n = blockIdx.x * 4 + wv;
  const float* p = part + (size_t)n * 64 + lane;
  float tot = 0.f;
#pragma unroll
  for (int z = 0; z < 8; ++z) tot += p[(size_t)z * NN * 64];
  float l = __shfl(tot, 50);
  float hv = (lane < H2DIM) ? lrelu(tot / l + b2[lane]) : 0.f;
  // FiLM
  int r32 = lane & 31;
  float locv = l_loc[n * 16 + (lane & 15)];
  float cov = __shfl(locv, 15);
  cov = fminf(fmaxf(cov, 0.f), 1.f);
  float a1v = bl1[r32];
#pragma unroll
  for (int j = 0; j < 16; ++j) a1v += Wl1[r32 * 16 + j] * __shfl(locv, j);
  float z1 = lrelu(a1v);
  float a2v = bl2[r32];
#pragma unroll
  for (int j = 0; j < 32; ++j) a2v += Wl2[r32 * 32 + j] * __shfl(z1, j);
  float z2 = lrelu(a2v);
  float gs = bgate[0];
  float gam, bet;
  {
    int o = lane < H2DIM ? lane : 0;
    gam = bg[o];
    bet = bb[o];
#pragma unroll
    for (int j = 0; j < 32; ++j) {
      float zj = __shfl(z2, j);
      gs += Wgate[j] * zj;
      gam += Wg[o * 32 + j] * zj;
      bet += Wb[o * 32 + j] * zj;
    }
  }
  float g = cov / (1.f + __expf(-gs));
  float hf = hv + g * (gam * hv + bet);
  int o = lane < H2DIM ? lane : 0;
  float p0 = lane < H2DIM ? hf * Wc[o] : 0.f;
  float p1 = lane < H2DIM ? hf * Wc[H2DIM + o] : 0.f;
  for (int off = 32; off > 0; off >>= 1) {
    p0 += __shfl_down(p0, off);
    p1 += __shfl_down(p1, off);
  }
  if (lane == 0) {
    logits[n * 2 + 0] = lrelu(p0);
    logits[n * 2 + 1] = lrelu(p1);
  }
}

// ---------------- SSDB stage A: 240 parallel dot-products (no atomics) ----------------
// grid (60 k, 4 combos), block 64: hsum[combo*60+k] = lrelu(dot + bs1[k]) * Ws2[k]
__global__ __launch_bounds__(64) void k_ssdbA(const float* __restrict__ logits,
                                              const float* __restrict__ Ws1, const float* __restrict__ bs1,
                                              const float* __restrict__ Ws2, float* __restrict__ hsum) {
  const int k = blockIdx.x, combo = blockIdx.y;
  const int hemi = combo >> 1, c = combo & 1;
  const int lane = threadIdx.x;
  const float* wr = Ws1 + (size_t)k * 2048;
  const float* lc = logits + (size_t)hemi * 4096 + c;
  float acc = 0.f;
#pragma unroll 4
  for (int i = lane; i < 2048; i += 64) acc += wr[i] * lc[2 * i];
  for (int off = 32; off > 0; off >>= 1) acc += __shfl_down(acc, off);
  if (lane == 0) hsum[combo * 60 + k] = lrelu(acc + bs1[k]) * Ws2[k];
}

// ---------------- SSDB stage B + final output ----------------
// grid 33 x 256: each block redundantly reduces hsum -> Bs[4], writes its out-slice
__global__ __launch_bounds__(256) void k_finB(const float* __restrict__ hsum,
                                              const float* __restrict__ bs2,
                                              const float* __restrict__ logits,
                                              float* __restrict__ out) {
  __shared__ float Bs[4];
  const int t = threadIdx.x;
  {
    int combo = t >> 6, k = t & 63;
    float v = (k < 60) ? hsum[combo * 60 + k] : 0.f;
    for (int off = 32; off > 0; off >>= 1) v += __shfl_down(v, off);
    if (k == 0) Bs[combo] = lrelu(v + bs2[0]);
  }
  __syncthreads();
  int id = blockIdx.x * 256 + t;
  if (id < 2 * NN) {
    int n = id >> 1, c = id & 1;
    out[id] = logits[id] + Bs[(n < 2048 ? 0 : 2) + c];
  } else if (id < 2 * NN + 2) {
    int c = id - 2 * NN;
    out[id] = 0.5f * (Bs[c] + Bs[2 + c]);
  }
}

// ---------------- workspace layout (float offsets) ----------------
#define OFF_BITS 0          // 4096*66 u64 = 540672 f
#define OFF_W1T 540672      // 128*4128 shorts = 264192 f
#define OFF_GP 804864       // [8][4096][128] = 4194304 f; A1P/A2P overlay
#define OFF_A1P 804864      // [4][4][4096][32] = 2097152
#define OFF_A2P 804864      // [8][4096][64] = 2097152
#define OFF_WH1BT 4999168   // 128*4128 shorts = 264192 f
#define OFF_F1A 5263360     // [4][4096]
#define OFF_F2A 5279744     // [4][4096]
#define OFF_WH2BT 5296128   // 64*4128 shorts = 132096 f
#define OFF_F12 5428224     // 4096
#define OFF_F22 5432320     // 4096
#define OFF_LOG 5436416     // 8192
#define OFF_MX 5444608      // 8 uints: [0..3]=mxu1, [4]=mxu2
#define OFF_HS 5444672      // 240 floats (ssdb hsum)

extern "C" void kernel_launch(void* const* d_in, const int* in_sizes, int n_in,
                              void* d_out, int out_size, void* d_ws, size_t ws_size,
                              hipStream_t stream) {
  const float* x_fc  = (const float*)d_in[0];
  const int*   adj   = (const int*)d_in[1];
  const float* l_loc = (const float*)d_in[2];
  const float* W1    = (const float*)d_in[3];
  const float* a1s   = (const float*)d_in[4];
  const float* a1d   = (const float*)d_in[5];
  const float* b1    = (const float*)d_in[6];
  const float* W2    = (const float*)d_in[7];
  const float* a2s   = (const float*)d_in[8];
  const float* a2d   = (const float*)d_in[9];
  const float* b2    = (const float*)d_in[10];
  const float* Wc    = (const float*)d_in[11];
  const float* Wl1   = (const float*)d_in[12];
  const float* bl1   = (const float*)d_in[13];
  const float* Wl2   = (const float*)d_in[14];
  const float* bl2   = (const float*)d_in[15];
  const float* Wg    = (const float*)d_in[16];
  const float* bg    = (const float*)d_in[17];
  const float* Wb    = (const float*)d_in[18];
  const float* bb    = (const float*)d_in[19];
  const float* Wgate = (const float*)d_in[20];
  const float* bgate = (const float*)d_in[21];
  const float* Ws1   = (const float*)d_in[22];
  const float* bs1   = (const float*)d_in[23];
  const float* Ws2   = (const float*)d_in[24];
  const float* bs2   = (const float*)d_in[25];
  float* out = (float*)d_out;
  float* w = (float*)d_ws;
  unsigned long long* bits = (unsigned long long*)(w + OFF_BITS);
  const unsigned int* bits32 = (const unsigned int*)bits;
  unsigned short* wh1bt = (unsigned short*)(w + OFF_WH1BT);
  unsigned short* wh2bt = (unsigned short*)(w + OFF_WH2BT);
  unsigned short* w1t = (unsigned short*)(w + OFF_W1T);
  unsigned* mxu = (unsigned*)(w + OFF_MX);

  hipMemsetAsync(mxu, 0, 8 * sizeof(unsigned), stream);  // encoded-domain minimum
  k_bits<<<NN * NN / 1024, 256, 0, stream>>>(adj, bits);
  k_prep<<<16, 256, 0, stream>>>(W1, a1s, a1d, w1t);
  k_gemm1s<<<dim3(128, 8), 256, 0, stream>>>(x_fc, w1t, w + OFF_GP);
  k_f1c<<<256, 256, 0, stream>>>(w + OFF_GP, wh1bt, w + OFF_F1A, w + OFF_F2A, mxu);
  k_att1m<<<dim3(64, HEADS, 4), 256, 0, stream>>>(wh1bt, w + OFF_F1A, w + OFF_F2A,
                                                  mxu, bits32, w + OFF_A1P);
  k_fuseA<<<1024, 256, 0, stream>>>(w + OFF_A1P, b1, W2, a2s, a2d, wh2bt,
                                    w + OFF_F12, w + OFF_F22, mxu + 4);
  k_att2m<<<dim3(64, 8), 256, 0, stream>>>(wh2bt, w + OFF_F12, w + OFF_F22,
                                           mxu + 4, bits32, w + OFF_A2P);
  k_fuseB<<<1024, 256, 0, stream>>>(w + OFF_A2P, b2, l_loc, Wl1, bl1, Wl2, bl2,
                                    Wg, bg, Wb, bb, Wgate, bgate, Wc, w + OFF_LOG);
  k_ssdbA<<<dim3(60, 4), 64, 0, stream>>>(w + OFF_LOG, Ws1, bs1, Ws2, w + OFF_HS);
  k_finB<<<33, 256, 0, stream>>>(w + OFF_HS, bs2, w + OFF_LOG, out);
}